// Round 6
// baseline (556.599 us; speedup 1.0000x reference)
//
#include <hip/hip_runtime.h>

// Bilinear scatter-add via 4x2-cell tile binning + register-tile gather.
// N=500000, D=112, H=64, W=176. NTILE=44x32=1408, ~666 entries/tile.
//
// R5 post-mortem: per-cell gather re-reads each feature row 4x
// (FETCH 475MB, accum 150us); fill writes 2M scattered entries (~140us).
// R6: tile bins cut entries 2M->937K (both kernels shrink). Thread c owns
// channel c with 8 REGISTER accumulators (no LDS atomics - R4 trap).
// Staging precomputes per-entry cell weights into a 32B LDS struct so the
// inner loop is 2x ds_read_b128 + 1 feat load + 2 mul + 8 fma per entry.
// Entry = raw p (4B) -> no weight quantization (absmax back to 0.0625).

#define D     112
#define H     64
#define W     176
#define TX    4
#define TY    2
#define TXN   (W / TX)      // 44
#define TYN   (H / TY)      // 32
#define NTILE (TXN * TYN)   // 1408
#define CAP   1024          // mean 666, sigma ~26 -> +13 sigma, safe

struct __align__(16) SEntry {
    float wxc0, wxc1, wxc2, wxc3;   // x-weight per tile column
    float wyc0, wyc1;               // y-weight per tile row
    int   prow;                     // p * D
    int   pad;
};

__global__ __launch_bounds__(256) void fill_kernel(
    const float2* __restrict__ pos,   // [N] (x, y)
    int* __restrict__ cnt,            // [NTILE], pre-zeroed
    int* __restrict__ bucket,         // [NTILE * CAP]
    int N)
{
    int p = blockIdx.x * blockDim.x + threadIdx.x;
    if (p >= N) return;

    float2 xy = pos[p];
    int x0 = (int)floorf(xy.x);
    int y0 = (int)floorf(xy.y);
    int x1 = x0 + 1, y1 = y0 + 1;

    int tx0 = x0 >> 2, ty0 = y0 >> 1;
    int tx1 = (x1 < W) ? (x1 >> 2) : tx0;
    int ty1 = (y1 < H) ? (y1 >> 1) : ty0;

    bool dx = (tx1 != tx0);
    bool dy = (ty1 != ty0);

    int t00 = ty0 * TXN + tx0;
    { int i = atomicAdd(&cnt[t00], 1); if (i < CAP) bucket[t00 * CAP + i] = p; }
    if (dx) {
        int tt = ty0 * TXN + tx1;
        int i = atomicAdd(&cnt[tt], 1); if (i < CAP) bucket[tt * CAP + i] = p;
    }
    if (dy) {
        int tt = ty1 * TXN + tx0;
        int i = atomicAdd(&cnt[tt], 1); if (i < CAP) bucket[tt * CAP + i] = p;
    }
    if (dx && dy) {
        int tt = ty1 * TXN + tx1;
        int i = atomicAdd(&cnt[tt], 1); if (i < CAP) bucket[tt * CAP + i] = p;
    }
}

__global__ __launch_bounds__(128) void accum_kernel(
    const float2* __restrict__ pos,
    const float* __restrict__ feat,   // [N, D]
    const int* __restrict__ cnt,
    const int* __restrict__ bucket,
    float* __restrict__ out)          // [H, W, D]
{
    const int tile = blockIdx.x;
    const int tileX0 = (tile % TXN) * TX;
    const int tileY0 = (tile / TXN) * TY;
    const int t = threadIdx.x;
    const int n = min(cnt[tile], CAP);
    const int* bk = bucket + tile * CAP;

    __shared__ SEntry se[128];        // 4 KB

    float a00 = 0.f, a01 = 0.f, a02 = 0.f, a03 = 0.f;
    float a10 = 0.f, a11 = 0.f, a12 = 0.f, a13 = 0.f;

    for (int base = 0; base < n; base += 128) {
        int m = min(128, n - base);
        if (t < m) {
            int p = bk[base + t];
            float2 xy = pos[p];             // pos = 4MB, L3-resident
            float x = xy.x - (float)tileX0; // tile-local coords
            float y = xy.y - (float)tileY0;
            float x0f = floorf(x), y0f = floorf(y);
            float wx = x - x0f, wy = y - y0f;
            int lx0 = (int)x0f;             // in [-1, 3]
            int ly0 = (int)y0f;             // in [-1, 1]
            SEntry e;
            e.wxc0 = (lx0 == 0) ? (1.f - wx) : ((lx0 == -1) ? wx : 0.f);
            e.wxc1 = (lx0 == 1) ? (1.f - wx) : ((lx0 ==  0) ? wx : 0.f);
            e.wxc2 = (lx0 == 2) ? (1.f - wx) : ((lx0 ==  1) ? wx : 0.f);
            e.wxc3 = (lx0 == 3) ? (1.f - wx) : ((lx0 ==  2) ? wx : 0.f);
            e.wyc0 = (ly0 == 0) ? (1.f - wy) : ((ly0 == -1) ? wy : 0.f);
            e.wyc1 = (ly0 == 1) ? (1.f - wy) : ((ly0 ==  0) ? wy : 0.f);
            e.prow = p * D;
            e.pad = 0;
            se[t] = e;                      // 2x ds_write_b128
        }
        __syncthreads();

        if (t < D) {
#pragma unroll 4
            for (int e2 = 0; e2 < m; ++e2) {
                SEntry en = se[e2];         // broadcast: 2x ds_read_b128
                float f = feat[en.prow + t];
                float fa = en.wyc0 * f;
                float fb = en.wyc1 * f;
                a00 = fmaf(en.wxc0, fa, a00);
                a01 = fmaf(en.wxc1, fa, a01);
                a02 = fmaf(en.wxc2, fa, a02);
                a03 = fmaf(en.wxc3, fa, a03);
                a10 = fmaf(en.wxc0, fb, a10);
                a11 = fmaf(en.wxc1, fb, a11);
                a12 = fmaf(en.wxc2, fb, a12);
                a13 = fmaf(en.wxc3, fb, a13);
            }
        }
        __syncthreads();
    }

    // Each cell belongs to exactly one tile -> plain stores, no memset(out).
    if (t < D) {
        float* o0 = out + (tileY0 * W + tileX0) * D + t;
        o0[0 * D] = a00; o0[1 * D] = a01; o0[2 * D] = a02; o0[3 * D] = a03;
        float* o1 = out + ((tileY0 + 1) * W + tileX0) * D + t;
        o1[0 * D] = a10; o1[1 * D] = a11; o1[2 * D] = a12; o1[3 * D] = a13;
    }
}

extern "C" void kernel_launch(void* const* d_in, const int* in_sizes, int n_in,
                              void* d_out, int out_size, void* d_ws, size_t ws_size,
                              hipStream_t stream) {
    const float2* pos = (const float2*)d_in[0];
    const float* feat = (const float*)d_in[1];
    float* out        = (float*)d_out;

    const int N = in_sizes[0] / 2;

    int* cnt    = (int*)d_ws;
    int* bucket = cnt + NTILE;
    // ws use: NTILE*4 + NTILE*CAP*4 B ~= 5.8 MB (16.2 MB proven available)

    hipMemsetAsync(cnt, 0, NTILE * sizeof(int), stream);

    int blocks = (N + 255) / 256;
    fill_kernel<<<blocks, 256, 0, stream>>>(pos, cnt, bucket, N);

    accum_kernel<<<NTILE, 128, 0, stream>>>(pos, feat, cnt, bucket, out);
}